// Round 10
// baseline (38.867 us; speedup 1.0000x reference)
//
#include <hip/hip_runtime.h>

constexpr int B   = 1024;
constexpr int T   = 8192;
constexpr int MS  = 128;
constexpr int NF4 = T / 2;     // 4096 2-t prefix entries per row
constexpr int PSTRIDE = 32;    // floats per partial slot = 128 B (one L2 line)

// Padded LDS index for prefix entry k (k in [0, 4096]): idx = k + (k>>4).
__device__ __forceinline__ int pidx(int k) { return k + (k >> 4); }

// Fused, third attempt — with the correct gfx942+ agent-scope mapping:
//   release -> buffer_wbl2 (writes back DIRTY lines only: ~free for this
//              read-mostly kernel), acquire -> buffer_inv (L2 nuke).
// Round 6 died on seq_cst fences in every wave (4096x wb+inv); round 8 died
// on ACQ_REL tickets (1024x mid-stream inv). Here: per block = plain stores
// to a PRIVATE 128B line + ONE RELEASE fetch_add (wb only). Exactly one
// ACQUIRE (one inv) happens in the single last block, after all streaming
// is complete. Partials padded to 128 B so non-coherent whole-line
// writebacks can't clobber a neighbor's half-line (false sharing).
__global__ __launch_bounds__(512, 8) void provence_fused_kernel(
    const float* __restrict__ rlogits,   // [B]
    const float* __restrict__ rlabels,   // [B]
    const float* __restrict__ logits,    // [B, T, 2]
    const int*   __restrict__ labels,    // [B, MS]
    const int*   __restrict__ bnd,       // [B, MS, 2]
    float*       __restrict__ partial,   // [B * PSTRIDE] 128B/block
    unsigned int* __restrict__ counter,  // own line; zeroed per call
    float*       __restrict__ out)       // [1]
{
    const int b    = blockIdx.x;
    const int tid  = threadIdx.x;
    const int lane = tid & 63;
    const int wave = tid >> 6;
    const float* row = logits + (size_t)b * T * 2;

    __shared__ float2 E2[NF4 + (NF4 >> 4) + 2];   // ~34.9 KB
    __shared__ float  wtot0[8], wtot1[8];
    __shared__ float  rn[8], rc[8], rb[8];
    __shared__ int    wemax[2];
    __shared__ bool   isLast;

    // ---- Phase 0: metadata; row BCE on thread 0; max valid end ----
    int s_ = -1, e_ = -1, lab_ = 0;
    if (tid < MS) {
        const size_t bm = (size_t)b * MS + tid;
        s_   = bnd[bm * 2 + 0];
        e_   = bnd[bm * 2 + 1];
        lab_ = labels[bm];
    }
    float bce_b = 0.f;
    if (tid == 0) {
        const float x = rlogits[b];
        const float y = rlabels[b];
        const float t = log1pf(expf(-fabsf(x)));
        bce_b = y * (fmaxf(-x, 0.f) + t) + (1.f - y) * (fmaxf(x, 0.f) + t);
    }
    int emax = (tid < MS && s_ != -1) ? min(max(e_, 0), T) : 0;
    #pragma unroll
    for (int off = 32; off > 0; off >>= 1)
        emax = max(emax, __shfl_down(emax, off, 64));
    if (wave < 2 && lane == 0) wemax[wave] = emax;   // segments live in waves 0-1
    __syncthreads();
    const int max_e = max(wemax[0], wemax[1]);

    // ---- Phase 1: per-thread 8 float4 loads, pair sums; skip past max_e ----
    float2 pair[8];                      // per-float4 (2-t) channel sums
    const int chunk_lo = tid << 4;       // first t of this thread's chunk
    if (chunk_lo < max_e) {
        const float4* p = reinterpret_cast<const float4*>(row) + (size_t)tid * 8;
        #pragma unroll
        for (int g = 0; g < 2; ++g) {
            float4 w0 = p[g * 4 + 0], w1 = p[g * 4 + 1];
            float4 w2 = p[g * 4 + 2], w3 = p[g * 4 + 3];
            pair[g * 4 + 0] = make_float2(w0.x + w0.z, w0.y + w0.w);
            pair[g * 4 + 1] = make_float2(w1.x + w1.z, w1.y + w1.w);
            pair[g * 4 + 2] = make_float2(w2.x + w2.z, w2.y + w2.w);
            pair[g * 4 + 3] = make_float2(w3.x + w3.z, w3.y + w3.w);
        }
    } else {
        #pragma unroll
        for (int j = 0; j < 8; ++j) pair[j] = make_float2(0.f, 0.f);
    }
    float ex0 = 0.f, ex1 = 0.f;
    #pragma unroll
    for (int j = 0; j < 8; ++j) { ex0 += pair[j].x; ex1 += pair[j].y; }

    // ---- Phase 2: scan of thread totals -> exclusive base; fill E2 ----
    float x0 = ex0, x1 = ex1;
    #pragma unroll
    for (int off = 1; off < 64; off <<= 1) {
        float y0 = __shfl_up(x0, off, 64);
        float y1 = __shfl_up(x1, off, 64);
        if (lane >= off) { x0 += y0; x1 += y1; }
    }
    if (lane == 63) { wtot0[wave] = x0; wtot1[wave] = x1; }
    __syncthreads();
    float pre0 = 0.f, pre1 = 0.f;
    #pragma unroll
    for (int w = 0; w < 7; ++w) {
        if (wave > w) { pre0 += wtot0[w]; pre1 += wtot1[w]; }
    }
    float run0 = x0 + pre0 - ex0, run1 = x1 + pre1 - ex1;   // exclusive base
    #pragma unroll
    for (int j = 0; j < 8; ++j) {       // entry k = prefix before float4 k
        const int k = 8 * tid + j;
        E2[pidx(k)] = make_float2(run0, run1);
        run0 += pair[j].x;
        run1 += pair[j].y;
    }
    if (tid == 511) E2[pidx(NF4)] = make_float2(run0, run1);  // k = 4096
    __syncthreads();

    // ---- Phase 3: per-segment NLL (parallel over 128 segments) ----
    float nll = 0.f, cnt = 0.f;
    if (tid < MS && s_ != -1) {
        const int sc = min(max(s_, 0), T);
        const int ec = min(max(e_, 0), T);
        const int cs = sc >> 1;
        const int ce = ec >> 1;

        const float2 Ps = E2[pidx(cs)];
        const float2 Pe = E2[pidx(ce)];
        float q0 = Pe.x - Ps.x;
        float q1 = Pe.y - Ps.y;
        if (sc & 1) {  // subtract element sc-1
            float2 u = *reinterpret_cast<const float2*>(row + (size_t)(sc - 1) * 2);
            q0 -= u.x; q1 -= u.y;
        }
        if (ec & 1) {  // add element ec-1
            float2 u = *reinterpret_cast<const float2*>(row + (size_t)(ec - 1) * 2);
            q0 += u.x; q1 += u.y;
        }

        const int len = ec - sc;
        float p0 = 0.f, p1 = 0.f;
        if (len > 0) {
            const float inv = 1.0f / (float)len;
            p0 = q0 * inv;
            p1 = q1 * inv;
        }
        const float mx  = fmaxf(p0, p1);
        const float lse = mx + logf(expf(p0 - mx) + expf(p1 - mx));
        nll = lse - ((lab_ == 0) ? p0 : p1);
        cnt = 1.0f;
    }

    // ---- Phase 4: block reduce ----
    #pragma unroll
    for (int off = 32; off > 0; off >>= 1) {
        nll += __shfl_down(nll, off, 64);
        cnt += __shfl_down(cnt, off, 64);
    }
    if (lane == 0) { rn[wave] = nll; rc[wave] = cnt; }
    __syncthreads();

    // ---- Phase 5: publish (plain stores, private line) + RELEASE ticket ----
    if (tid == 0) {
        float tn = 0.f, tc = 0.f;
        #pragma unroll
        for (int w = 0; w < 8; ++w) { tn += rn[w]; tc += rc[w]; }
        float* mine = partial + (size_t)b * PSTRIDE;
        mine[0] = tn; mine[1] = tc; mine[2] = bce_b;
        // release: vmcnt drain + buffer_wbl2 (dirty lines only — cheap) + add
        const unsigned int old = __hip_atomic_fetch_add(
            counter, 1u, __ATOMIC_RELEASE, __HIP_MEMORY_SCOPE_AGENT);
        if (old == (unsigned int)(B - 1)) {
            // the ONE acquire (one buffer_inv) in the whole grid, issued
            // after every block has finished streaming and released.
            (void)__hip_atomic_load(counter, __ATOMIC_ACQUIRE,
                                    __HIP_MEMORY_SCOPE_AGENT);
            isLast = true;
        } else {
            isLast = false;
        }
    }
    __syncthreads();
    if (!isLast) return;

    // ---- Phase 6: last block reduces all partials (fixed order) ----
    float fn = 0.f, fc = 0.f, fb = 0.f;
    #pragma unroll
    for (int i = 0; i < 2; ++i) {
        const float* p = partial + (size_t)(tid + i * 512) * PSTRIDE;
        fn += p[0]; fc += p[1]; fb += p[2];
    }
    #pragma unroll
    for (int off = 32; off > 0; off >>= 1) {
        fn += __shfl_down(fn, off, 64);
        fc += __shfl_down(fc, off, 64);
        fb += __shfl_down(fb, off, 64);
    }
    if (lane == 0) { rn[wave] = fn; rc[wave] = fc; rb[wave] = fb; }
    __syncthreads();
    if (tid == 0) {
        float tn = 0.f, tc = 0.f, tb = 0.f;
        #pragma unroll
        for (int w = 0; w < 8; ++w) { tn += rn[w]; tc += rc[w]; tb += rb[w]; }
        const float rank  = tb / (float)B;
        const float prune = (tc > 0.f) ? (tn / tc) : 0.f;
        out[0] = 1.0f * rank + 0.5f * prune;
    }
}

extern "C" void kernel_launch(void* const* d_in, const int* in_sizes, int n_in,
                              void* d_out, int out_size, void* d_ws, size_t ws_size,
                              hipStream_t stream) {
    const float* rlogits = (const float*)d_in[0];  // ranking_logits [B]
    const float* rlabels = (const float*)d_in[1];  // ranking_labels [B]
    const float* plogits = (const float*)d_in[2];  // pruning_logits [B,T,C]
    const int*   plabels = (const int*)  d_in[3];  // pruning_labels [B,MS]
    const int*   bnd     = (const int*)  d_in[4];  // boundaries [B,MS,2]

    float* out     = (float*)d_out;
    float* partial = (float*)d_ws;                 // B lines of 128 B
    unsigned int* counter =
        (unsigned int*)((char*)d_ws + (size_t)B * PSTRIDE * sizeof(float));

    // Counter must be 0 at kernel start on every call (first call sees
    // poisoned d_ws; replays must not inherit state).
    hipMemsetAsync(counter, 0, sizeof(unsigned int), stream);

    provence_fused_kernel<<<B, 512, 0, stream>>>(
        rlogits, rlabels, plogits, plabels, bnd, partial, counter, out);
}